// Round 6
// baseline (485.969 us; speedup 1.0000x reference)
//
#include <hip/hip_runtime.h>
#include <math.h>

#define NN 50000
#define NE 800000
#define DIN 128
#define DH 64
#define NG 64

#define GEMM_BLOCKS ((NN + 63) / 64)   // 782
#define DEG_BLOCKS 2048
#define FILL_BLOCKS 2048

// ---------------- hybrid: gemm layer1 + degree histogram (independent work) ----------------
// Blocks [0, GEMM_BLOCKS) compute tmp = x @ W1 (register-tiled, see gemm_kernel).
// Blocks [GEMM_BLOCKS, GEMM_BLOCKS+DEG_BLOCKS) do the indeg atomic histogram.
// Both are independent; fusing hides the histogram latency under the GEMM.
template <int K>
__global__ __launch_bounds__(256, 4) void gemm_deg_kernel(const float* __restrict__ in,
                                                          const float* __restrict__ W,
                                                          float* __restrict__ out, int n,
                                                          const int* __restrict__ col,
                                                          int* __restrict__ indeg, int e) {
    __shared__ float Ws[K * 64];
    if (blockIdx.x >= GEMM_BLOCKS) {
        int i = (blockIdx.x - GEMM_BLOCKS) * 256 + threadIdx.x;
        int stride = DEG_BLOCKS * 256;
        for (; i < e; i += stride) atomicAdd(&indeg[col[i]], 1);
        return;
    }
    for (int t = threadIdx.x; t < K * 16; t += 256)
        reinterpret_cast<float4*>(Ws)[t] = reinterpret_cast<const float4*>(W)[t];
    __syncthreads();

    int w = threadIdx.x >> 6, l = threadIdx.x & 63;
    int fq = l & 15;
    int nl = l >> 4;
    int base = blockIdx.x * 64 + w * 16 + nl * 4;

    const float* r0 = in + (size_t)min(base + 0, n - 1) * K;
    const float* r1 = in + (size_t)min(base + 1, n - 1) * K;
    const float* r2 = in + (size_t)min(base + 2, n - 1) * K;
    const float* r3 = in + (size_t)min(base + 3, n - 1) * K;

    float acc[4][4];
    #pragma unroll
    for (int i = 0; i < 4; ++i)
        #pragma unroll
        for (int f = 0; f < 4; ++f) acc[i][f] = 0.f;

    #pragma unroll 2
    for (int k = 0; k < K; k += 4) {
        float4 wv[4];
        #pragma unroll
        for (int kk = 0; kk < 4; ++kk)
            wv[kk] = *reinterpret_cast<const float4*>(&Ws[(k + kk) * 64 + 4 * fq]);
        float4 xv[4];
        xv[0] = *reinterpret_cast<const float4*>(r0 + k);
        xv[1] = *reinterpret_cast<const float4*>(r1 + k);
        xv[2] = *reinterpret_cast<const float4*>(r2 + k);
        xv[3] = *reinterpret_cast<const float4*>(r3 + k);
        #pragma unroll
        for (int i = 0; i < 4; ++i) {
            float xs[4] = {xv[i].x, xv[i].y, xv[i].z, xv[i].w};
            #pragma unroll
            for (int kk = 0; kk < 4; ++kk) {
                acc[i][0] = fmaf(xs[kk], wv[kk].x, acc[i][0]);
                acc[i][1] = fmaf(xs[kk], wv[kk].y, acc[i][1]);
                acc[i][2] = fmaf(xs[kk], wv[kk].z, acc[i][2]);
                acc[i][3] = fmaf(xs[kk], wv[kk].w, acc[i][3]);
            }
        }
    }

    #pragma unroll
    for (int i = 0; i < 4; ++i) {
        int node = base + i;
        if (node < n) {
            float4 o = make_float4(acc[i][0], acc[i][1], acc[i][2], acc[i][3]);
            *reinterpret_cast<float4*>(&out[(size_t)node * 64 + 4 * fq]) = o;
        }
    }
}

// ---------------- GEMM (layers 2,3): out[N,64] = in[N,64] @ W[64,64] ----------------
// Round-4 lesson: full K unroll -> 256 VGPR + scratch spill (447us). unroll 2 +
// launch_bounds(256,4) keeps it in-register.
template <int K>
__global__ __launch_bounds__(256, 4) void gemm_kernel(const float* __restrict__ in,
                                                      const float* __restrict__ W,
                                                      float* __restrict__ out, int n) {
    __shared__ float Ws[K * 64];
    for (int t = threadIdx.x; t < K * 16; t += 256)
        reinterpret_cast<float4*>(Ws)[t] = reinterpret_cast<const float4*>(W)[t];
    __syncthreads();

    int w = threadIdx.x >> 6, l = threadIdx.x & 63;
    int fq = l & 15;
    int nl = l >> 4;
    int base = blockIdx.x * 64 + w * 16 + nl * 4;

    const float* r0 = in + (size_t)min(base + 0, n - 1) * K;
    const float* r1 = in + (size_t)min(base + 1, n - 1) * K;
    const float* r2 = in + (size_t)min(base + 2, n - 1) * K;
    const float* r3 = in + (size_t)min(base + 3, n - 1) * K;

    float acc[4][4];
    #pragma unroll
    for (int i = 0; i < 4; ++i)
        #pragma unroll
        for (int f = 0; f < 4; ++f) acc[i][f] = 0.f;

    #pragma unroll 2
    for (int k = 0; k < K; k += 4) {
        float4 wv[4];
        #pragma unroll
        for (int kk = 0; kk < 4; ++kk)
            wv[kk] = *reinterpret_cast<const float4*>(&Ws[(k + kk) * 64 + 4 * fq]);
        float4 xv[4];
        xv[0] = *reinterpret_cast<const float4*>(r0 + k);
        xv[1] = *reinterpret_cast<const float4*>(r1 + k);
        xv[2] = *reinterpret_cast<const float4*>(r2 + k);
        xv[3] = *reinterpret_cast<const float4*>(r3 + k);
        #pragma unroll
        for (int i = 0; i < 4; ++i) {
            float xs[4] = {xv[i].x, xv[i].y, xv[i].z, xv[i].w};
            #pragma unroll
            for (int kk = 0; kk < 4; ++kk) {
                acc[i][0] = fmaf(xs[kk], wv[kk].x, acc[i][0]);
                acc[i][1] = fmaf(xs[kk], wv[kk].y, acc[i][1]);
                acc[i][2] = fmaf(xs[kk], wv[kk].z, acc[i][2]);
                acc[i][3] = fmaf(xs[kk], wv[kk].w, acc[i][3]);
            }
        }
    }

    #pragma unroll
    for (int i = 0; i < 4; ++i) {
        int node = base + i;
        if (node < n) {
            float4 o = make_float4(acc[i][0], acc[i][1], acc[i][2], acc[i][3]);
            *reinterpret_cast<float4*>(&out[(size_t)node * 64 + 4 * fq]) = o;
        }
    }
}

// ---------------- fused scan + dinv + cursor-init (single block, per-thread chunks) ----------------
// Round-5 lesson: the 49-iteration barrier-loop scan is latency-bound (~20us on 1 CU).
// Per-thread-chunk version: local sum -> ONE block scan -> local prefix writeback,
// and dinv/cursor are computed in the same phase-2 pass (kills 2 launches).
__global__ __launch_bounds__(1024) void scan_fuse_kernel(const int* __restrict__ indeg,
                                                         int* __restrict__ off,
                                                         int* __restrict__ cursor,
                                                         float* __restrict__ dinv, int n) {
    __shared__ int wsum[16];
    const int P = (n + 1023) / 1024;   // 49 elements per thread
    int t = threadIdx.x;
    int lane = t & 63, wid = t >> 6;
    int lo = t * P;
    int hi = lo + P; if (hi > n) hi = n;

    int s = 0;
    for (int i = lo; i < hi; ++i) s += indeg[i];

    // block-wide exclusive scan of per-thread sums
    int v = s;
    #pragma unroll
    for (int d = 1; d < 64; d <<= 1) {
        int u = __shfl_up(v, d, 64);
        if (lane >= d) v += u;
    }
    if (lane == 63) wsum[wid] = v;
    __syncthreads();
    if (wid == 0) {
        int wv = (lane < 16) ? wsum[lane] : 0;
        #pragma unroll
        for (int d = 1; d < 16; d <<= 1) {
            int u = __shfl_up(wv, d, 64);
            if (lane >= d) wv += u;
        }
        if (lane < 16) wsum[lane] = wv;
    }
    __syncthreads();
    int prefix = ((wid == 0) ? 0 : wsum[wid - 1]) + (v - s);   // exclusive for this thread

    int run = prefix;
    for (int i = lo; i < hi; ++i) {
        int d = indeg[i];
        off[i] = run;
        cursor[i] = run;
        dinv[i] = rsqrtf((float)(d + 1));
        run += d;
    }
    if (t == 1023) off[n] = run;   // thread 1023's chunk is empty or last -> run == total
}

// bucket edges by target: ew[p] = { bitcast(src), dinv[src]*dinv[col] }
__global__ void fill_kernel(const int* __restrict__ row, const int* __restrict__ col,
                            const float* __restrict__ dinv, int* __restrict__ cursor,
                            float2* __restrict__ ew, int e) {
    int i = blockIdx.x * blockDim.x + threadIdx.x;
    int stride = gridDim.x * blockDim.x;
    for (; i < e; i += stride) {
        int c = col[i], r = row[i];
        int p = atomicAdd(&cursor[c], 1);
        ew[p] = make_float2(__int_as_float(r), dinv[r] * dinv[c]);
    }
}

// ---------------- pull aggregation + bias + ELU: one wave per node, lane = feature ----------------
// Unroll 8: 8 outstanding metadata loads + 8 row gathers per wave iteration.
__global__ __launch_bounds__(256) void pull_kernel(const float* __restrict__ tmp,
                                                   const int* __restrict__ off,
                                                   const float2* __restrict__ ew,
                                                   const float* __restrict__ dinv,
                                                   const float* __restrict__ bias,
                                                   float* __restrict__ out, int n) {
    int wid = threadIdx.x >> 6;
    int lane = threadIdx.x & 63;
    int node = blockIdx.x * 4 + wid;
    if (node >= n) return;
    float dt = dinv[node];
    float acc = tmp[(size_t)node * 64 + lane] * dt * dt;   // self loop
    int e = off[node], s1 = off[node + 1];
    for (; e + 8 <= s1; e += 8) {
        float2 m[8];
        #pragma unroll
        for (int q = 0; q < 8; ++q) m[q] = ew[e + q];
        float v[8];
        #pragma unroll
        for (int q = 0; q < 8; ++q) v[q] = tmp[(size_t)__float_as_int(m[q].x) * 64 + lane];
        #pragma unroll
        for (int q = 0; q < 8; ++q) acc = fmaf(v[q], m[q].y, acc);
    }
    for (; e < s1; ++e) {
        float2 m = ew[e];
        acc = fmaf(tmp[(size_t)__float_as_int(m.x) * 64 + lane], m.y, acc);
    }
    float v = acc + bias[lane];
    out[(size_t)node * 64 + lane] = (v > 0.f) ? v : expm1f(v);
}

// ---------------- final linear + grouped mean-pool partials ----------------
#define POOL_BLOCKS 256
__global__ __launch_bounds__(256) void final_pool_kernel(const float* __restrict__ h,
                                                         const float* __restrict__ Wl,
                                                         const int* __restrict__ batch,
                                                         float* __restrict__ gsum,
                                                         float* __restrict__ gcnt, int n) {
    __shared__ float lsum[NG];
    __shared__ float lcnt[NG];
    if (threadIdx.x < NG) { lsum[threadIdx.x] = 0.f; lcnt[threadIdx.x] = 0.f; }
    __syncthreads();
    int wid = threadIdx.x >> 6, lane = threadIdx.x & 63;
    float wl = Wl[lane];
    int per_block = (n + POOL_BLOCKS - 1) / POOL_BLOCKS;
    int start = blockIdx.x * per_block;
    int end = start + per_block;
    if (end > n) end = n;
    for (int node = start + wid; node < end; node += 4) {
        float p = h[(size_t)node * 64 + lane] * wl;
        #pragma unroll
        for (int d = 32; d >= 1; d >>= 1) p += __shfl_xor(p, d, 64);
        if (lane == 0) {
            int g = batch[node];
            atomicAdd(&lsum[g], p);
            atomicAdd(&lcnt[g], 1.f);
        }
    }
    __syncthreads();
    if (threadIdx.x < NG && lcnt[threadIdx.x] != 0.f) {
        atomicAdd(&gsum[threadIdx.x], lsum[threadIdx.x]);
        atomicAdd(&gcnt[threadIdx.x], lcnt[threadIdx.x]);
    }
}

__global__ void pool_div_kernel(const float* __restrict__ gsum, const float* __restrict__ gcnt,
                                const float* __restrict__ bl, float* __restrict__ out) {
    int g = threadIdx.x;
    if (g < NG) {
        float c = gcnt[g];
        out[g] = (c > 0.5f) ? (gsum[g] / c + bl[0]) : 0.f;
    }
}

extern "C" void kernel_launch(void* const* d_in, const int* in_sizes, int n_in,
                              void* d_out, int out_size, void* d_ws, size_t ws_size,
                              hipStream_t stream) {
    const float* x    = (const float*)d_in[0];
    const int*   eidx = (const int*)d_in[1];
    const int*   row  = eidx;              // edge_index[0] = sources
    const int*   col  = eidx + NE;         // edge_index[1] = targets
    const int*   batch = (const int*)d_in[2];
    const float* W1 = (const float*)d_in[3];
    const float* b1 = (const float*)d_in[4];
    const float* W2 = (const float*)d_in[5];
    const float* b2 = (const float*)d_in[6];
    const float* W3 = (const float*)d_in[7];
    const float* b3 = (const float*)d_in[8];
    const float* Wl = (const float*)d_in[9];
    const float* bl = (const float*)d_in[10];
    float* out = (float*)d_out;

    // workspace layout (all offsets 64-element = 256B aligned)
    size_t cur = 0;
    auto take = [&](size_t elems) { size_t c = cur; cur += (elems + 63) & ~(size_t)63; return c; };
    float* base_f = (float*)d_ws;
    int*   base_i = (int*)d_ws;

    float*  dinv    = base_f + take(NN);
    int*    indeg   = base_i + take(NN);
    int*    csr_off = base_i + take(NN + 1);
    int*    cursor  = base_i + take(NN);
    float2* ew      = (float2*)(base_f + take((size_t)NE * 2));
    float*  tmp     = base_f + take((size_t)NN * 64);
    float*  h       = base_f + take((size_t)NN * 64);
    float*  gg      = base_f + take(2 * NG);   // gsum | gcnt contiguous
    float*  gsum    = gg;
    float*  gcnt    = gg + NG;
    (void)ws_size; (void)n_in; (void)in_sizes; (void)out_size;

    hipMemsetAsync(indeg, 0, NN * sizeof(int), stream);
    hipMemsetAsync(gg, 0, 2 * NG * sizeof(float), stream);

    const int nblk_pull = (NN + 3) / 4;

    // ---- layer-1 GEMM fused with degree histogram (independent) ----
    gemm_deg_kernel<DIN><<<GEMM_BLOCKS + DEG_BLOCKS, 256, 0, stream>>>(
        x, W1, tmp, NN, col, indeg, NE);
    // ---- scan + dinv + cursor in one single-block kernel ----
    scan_fuse_kernel<<<1, 1024, 0, stream>>>(indeg, csr_off, cursor, dinv, NN);
    // ---- CSR fill (2048 blocks: round-5 showed 32% occupancy at 1024) ----
    fill_kernel<<<FILL_BLOCKS, 256, 0, stream>>>(row, col, dinv, cursor, ew, NE);

    // ---- layer 1 pull ----
    pull_kernel<<<nblk_pull, 256, 0, stream>>>(tmp, csr_off, ew, dinv, b1, h, NN);

    // ---- layer 2 ----
    gemm_kernel<DH><<<GEMM_BLOCKS, 256, 0, stream>>>(h, W2, tmp, NN);
    pull_kernel<<<nblk_pull, 256, 0, stream>>>(tmp, csr_off, ew, dinv, b2, h, NN);

    // ---- layer 3 ----
    gemm_kernel<DH><<<GEMM_BLOCKS, 256, 0, stream>>>(h, W3, tmp, NN);
    pull_kernel<<<nblk_pull, 256, 0, stream>>>(tmp, csr_off, ew, dinv, b3, h, NN);

    // ---- final linear + mean pool ----
    final_pool_kernel<<<POOL_BLOCKS, 256, 0, stream>>>(h, Wl, batch, gsum, gcnt, NN);
    pool_div_kernel<<<1, 64, 0, stream>>>(gsum, gcnt, bl, out);
}

// Round 7
// 355.987 us; speedup vs baseline: 1.3651x; 1.3651x over previous
//
#include <hip/hip_runtime.h>
#include <math.h>

#define NN 50000
#define NE 800000
#define DIN 128
#define DH 64
#define NG 64

#define GEMM_BLOCKS ((NN + 63) / 64)     // 782
#define DEG_BLOCKS 2048
#define FILL_BLOCKS 2048
#define SCAN_BLOCKS ((NN + 255) / 256)   // 196

// ---------------- hybrid: gemm layer1 + degree histogram (independent work) ----------------
template <int K>
__global__ __launch_bounds__(256, 4) void gemm_deg_kernel(const float* __restrict__ in,
                                                          const float* __restrict__ W,
                                                          float* __restrict__ out, int n,
                                                          const int* __restrict__ col,
                                                          int* __restrict__ indeg, int e) {
    __shared__ float Ws[K * 64];
    if (blockIdx.x >= GEMM_BLOCKS) {
        int i = (blockIdx.x - GEMM_BLOCKS) * 256 + threadIdx.x;
        int stride = DEG_BLOCKS * 256;
        for (; i < e; i += stride) atomicAdd(&indeg[col[i]], 1);
        return;
    }
    for (int t = threadIdx.x; t < K * 16; t += 256)
        reinterpret_cast<float4*>(Ws)[t] = reinterpret_cast<const float4*>(W)[t];
    __syncthreads();

    int w = threadIdx.x >> 6, l = threadIdx.x & 63;
    int fq = l & 15;
    int nl = l >> 4;
    int base = blockIdx.x * 64 + w * 16 + nl * 4;

    const float* r0 = in + (size_t)min(base + 0, n - 1) * K;
    const float* r1 = in + (size_t)min(base + 1, n - 1) * K;
    const float* r2 = in + (size_t)min(base + 2, n - 1) * K;
    const float* r3 = in + (size_t)min(base + 3, n - 1) * K;

    float acc[4][4];
    #pragma unroll
    for (int i = 0; i < 4; ++i)
        #pragma unroll
        for (int f = 0; f < 4; ++f) acc[i][f] = 0.f;

    #pragma unroll 2
    for (int k = 0; k < K; k += 4) {
        float4 wv[4];
        #pragma unroll
        for (int kk = 0; kk < 4; ++kk)
            wv[kk] = *reinterpret_cast<const float4*>(&Ws[(k + kk) * 64 + 4 * fq]);
        float4 xv[4];
        xv[0] = *reinterpret_cast<const float4*>(r0 + k);
        xv[1] = *reinterpret_cast<const float4*>(r1 + k);
        xv[2] = *reinterpret_cast<const float4*>(r2 + k);
        xv[3] = *reinterpret_cast<const float4*>(r3 + k);
        #pragma unroll
        for (int i = 0; i < 4; ++i) {
            float xs[4] = {xv[i].x, xv[i].y, xv[i].z, xv[i].w};
            #pragma unroll
            for (int kk = 0; kk < 4; ++kk) {
                acc[i][0] = fmaf(xs[kk], wv[kk].x, acc[i][0]);
                acc[i][1] = fmaf(xs[kk], wv[kk].y, acc[i][1]);
                acc[i][2] = fmaf(xs[kk], wv[kk].z, acc[i][2]);
                acc[i][3] = fmaf(xs[kk], wv[kk].w, acc[i][3]);
            }
        }
    }

    #pragma unroll
    for (int i = 0; i < 4; ++i) {
        int node = base + i;
        if (node < n) {
            float4 o = make_float4(acc[i][0], acc[i][1], acc[i][2], acc[i][3]);
            *reinterpret_cast<float4*>(&out[(size_t)node * 64 + 4 * fq]) = o;
        }
    }
}

// ---------------- GEMM (layers 2,3) ----------------
// Round-4 lesson: full K unroll -> 256 VGPR + scratch spill. unroll 2 + lb(256,4).
template <int K>
__global__ __launch_bounds__(256, 4) void gemm_kernel(const float* __restrict__ in,
                                                      const float* __restrict__ W,
                                                      float* __restrict__ out, int n) {
    __shared__ float Ws[K * 64];
    for (int t = threadIdx.x; t < K * 16; t += 256)
        reinterpret_cast<float4*>(Ws)[t] = reinterpret_cast<const float4*>(W)[t];
    __syncthreads();

    int w = threadIdx.x >> 6, l = threadIdx.x & 63;
    int fq = l & 15;
    int nl = l >> 4;
    int base = blockIdx.x * 64 + w * 16 + nl * 4;

    const float* r0 = in + (size_t)min(base + 0, n - 1) * K;
    const float* r1 = in + (size_t)min(base + 1, n - 1) * K;
    const float* r2 = in + (size_t)min(base + 2, n - 1) * K;
    const float* r3 = in + (size_t)min(base + 3, n - 1) * K;

    float acc[4][4];
    #pragma unroll
    for (int i = 0; i < 4; ++i)
        #pragma unroll
        for (int f = 0; f < 4; ++f) acc[i][f] = 0.f;

    #pragma unroll 2
    for (int k = 0; k < K; k += 4) {
        float4 wv[4];
        #pragma unroll
        for (int kk = 0; kk < 4; ++kk)
            wv[kk] = *reinterpret_cast<const float4*>(&Ws[(k + kk) * 64 + 4 * fq]);
        float4 xv[4];
        xv[0] = *reinterpret_cast<const float4*>(r0 + k);
        xv[1] = *reinterpret_cast<const float4*>(r1 + k);
        xv[2] = *reinterpret_cast<const float4*>(r2 + k);
        xv[3] = *reinterpret_cast<const float4*>(r3 + k);
        #pragma unroll
        for (int i = 0; i < 4; ++i) {
            float xs[4] = {xv[i].x, xv[i].y, xv[i].z, xv[i].w};
            #pragma unroll
            for (int kk = 0; kk < 4; ++kk) {
                acc[i][0] = fmaf(xs[kk], wv[kk].x, acc[i][0]);
                acc[i][1] = fmaf(xs[kk], wv[kk].y, acc[i][1]);
                acc[i][2] = fmaf(xs[kk], wv[kk].z, acc[i][2]);
                acc[i][3] = fmaf(xs[kk], wv[kk].w, acc[i][3]);
            }
        }
    }

    #pragma unroll
    for (int i = 0; i < 4; ++i) {
        int node = base + i;
        if (node < n) {
            float4 o = make_float4(acc[i][0], acc[i][1], acc[i][2], acc[i][3]);
            *reinterpret_cast<float4*>(&out[(size_t)node * 64 + 4 * fq]) = o;
        }
    }
}

// ---------------- 3-phase coalesced multi-block scan ----------------
// Round-6 lesson: per-thread-chunk scan on 1 block = uncoalesced (64 lines per
// wave-load) + zero TLP -> 135us. This version: every access coalesced, 196
// blocks parallel; dinv/cursor fused into phase C.
__global__ __launch_bounds__(256) void scan_phaseA(const int* __restrict__ indeg,
                                                   int* __restrict__ partial, int n) {
    int i = blockIdx.x * 256 + threadIdx.x;
    int v = (i < n) ? indeg[i] : 0;
    int s = v;
    #pragma unroll
    for (int d = 1; d < 64; d <<= 1) s += __shfl_xor(s, d, 64);
    __shared__ int ws[4];
    if ((threadIdx.x & 63) == 0) ws[threadIdx.x >> 6] = s;
    __syncthreads();
    if (threadIdx.x == 0) partial[blockIdx.x] = ws[0] + ws[1] + ws[2] + ws[3];
}

__global__ __launch_bounds__(256) void scan_phaseB(int* __restrict__ partial, int nb) {
    int t = threadIdx.x;
    int lane = t & 63, wid = t >> 6;
    int v = (t < nb) ? partial[t] : 0;
    int inc = v;
    #pragma unroll
    for (int d = 1; d < 64; d <<= 1) {
        int u = __shfl_up(inc, d, 64);
        if (lane >= d) inc += u;
    }
    __shared__ int ws[4];
    if (lane == 63) ws[wid] = inc;
    __syncthreads();
    int woff = 0;
    #pragma unroll
    for (int k = 0; k < 4; ++k) woff += (k < wid) ? ws[k] : 0;
    if (t < nb) partial[t] = woff + inc - v;   // exclusive
}

__global__ __launch_bounds__(256) void scan_phaseC(const int* __restrict__ indeg,
                                                   const int* __restrict__ partial,
                                                   int* __restrict__ off,
                                                   int* __restrict__ cursor,
                                                   float* __restrict__ dinv, int n) {
    int i = blockIdx.x * 256 + threadIdx.x;
    int d = (i < n) ? indeg[i] : 0;
    int lane = threadIdx.x & 63, wid = threadIdx.x >> 6;
    int inc = d;
    #pragma unroll
    for (int dd = 1; dd < 64; dd <<= 1) {
        int u = __shfl_up(inc, dd, 64);
        if (lane >= dd) inc += u;
    }
    __shared__ int ws[4];
    if (lane == 63) ws[wid] = inc;
    __syncthreads();
    int woff = 0;
    #pragma unroll
    for (int k = 0; k < 4; ++k) woff += (k < wid) ? ws[k] : 0;
    int excl = partial[blockIdx.x] + woff + inc - d;
    if (i < n) {
        off[i] = excl;
        cursor[i] = excl;
        dinv[i] = rsqrtf((float)(d + 1));
        if (i == n - 1) off[n] = excl + d;
    }
}

// bucket edges by target: ew[p] = { bitcast(src), dinv[src]*dinv[col] }
__global__ void fill_kernel(const int* __restrict__ row, const int* __restrict__ col,
                            const float* __restrict__ dinv, int* __restrict__ cursor,
                            float2* __restrict__ ew, int e) {
    int i = blockIdx.x * blockDim.x + threadIdx.x;
    int stride = gridDim.x * blockDim.x;
    for (; i < e; i += stride) {
        int c = col[i], r = row[i];
        int p = atomicAdd(&cursor[c], 1);
        ew[p] = make_float2(__int_as_float(r), dinv[r] * dinv[c]);
    }
}

// ---------------- pull aggregation + bias + ELU: one wave per node, lane = feature ----------------
__global__ __launch_bounds__(256) void pull_kernel(const float* __restrict__ tmp,
                                                   const int* __restrict__ off,
                                                   const float2* __restrict__ ew,
                                                   const float* __restrict__ dinv,
                                                   const float* __restrict__ bias,
                                                   float* __restrict__ out, int n) {
    int wid = threadIdx.x >> 6;
    int lane = threadIdx.x & 63;
    int node = blockIdx.x * 4 + wid;
    if (node >= n) return;
    float dt = dinv[node];
    float acc = tmp[(size_t)node * 64 + lane] * dt * dt;   // self loop
    int e = off[node], s1 = off[node + 1];
    for (; e + 8 <= s1; e += 8) {
        float2 m[8];
        #pragma unroll
        for (int q = 0; q < 8; ++q) m[q] = ew[e + q];
        float v[8];
        #pragma unroll
        for (int q = 0; q < 8; ++q) v[q] = tmp[(size_t)__float_as_int(m[q].x) * 64 + lane];
        #pragma unroll
        for (int q = 0; q < 8; ++q) acc = fmaf(v[q], m[q].y, acc);
    }
    for (; e < s1; ++e) {
        float2 m = ew[e];
        acc = fmaf(tmp[(size_t)__float_as_int(m.x) * 64 + lane], m.y, acc);
    }
    float v = acc + bias[lane];
    out[(size_t)node * 64 + lane] = (v > 0.f) ? v : expm1f(v);
}

// ---------------- final linear + grouped mean-pool partials ----------------
#define POOL_BLOCKS 256
__global__ __launch_bounds__(256) void final_pool_kernel(const float* __restrict__ h,
                                                         const float* __restrict__ Wl,
                                                         const int* __restrict__ batch,
                                                         float* __restrict__ gsum,
                                                         float* __restrict__ gcnt, int n) {
    __shared__ float lsum[NG];
    __shared__ float lcnt[NG];
    if (threadIdx.x < NG) { lsum[threadIdx.x] = 0.f; lcnt[threadIdx.x] = 0.f; }
    __syncthreads();
    int wid = threadIdx.x >> 6, lane = threadIdx.x & 63;
    float wl = Wl[lane];
    int per_block = (n + POOL_BLOCKS - 1) / POOL_BLOCKS;
    int start = blockIdx.x * per_block;
    int end = start + per_block;
    if (end > n) end = n;
    for (int node = start + wid; node < end; node += 4) {
        float p = h[(size_t)node * 64 + lane] * wl;
        #pragma unroll
        for (int d = 32; d >= 1; d >>= 1) p += __shfl_xor(p, d, 64);
        if (lane == 0) {
            int g = batch[node];
            atomicAdd(&lsum[g], p);
            atomicAdd(&lcnt[g], 1.f);
        }
    }
    __syncthreads();
    if (threadIdx.x < NG && lcnt[threadIdx.x] != 0.f) {
        atomicAdd(&gsum[threadIdx.x], lsum[threadIdx.x]);
        atomicAdd(&gcnt[threadIdx.x], lcnt[threadIdx.x]);
    }
}

__global__ void pool_div_kernel(const float* __restrict__ gsum, const float* __restrict__ gcnt,
                                const float* __restrict__ bl, float* __restrict__ out) {
    int g = threadIdx.x;
    if (g < NG) {
        float c = gcnt[g];
        out[g] = (c > 0.5f) ? (gsum[g] / c + bl[0]) : 0.f;
    }
}

extern "C" void kernel_launch(void* const* d_in, const int* in_sizes, int n_in,
                              void* d_out, int out_size, void* d_ws, size_t ws_size,
                              hipStream_t stream) {
    const float* x    = (const float*)d_in[0];
    const int*   eidx = (const int*)d_in[1];
    const int*   row  = eidx;              // edge_index[0] = sources
    const int*   col  = eidx + NE;         // edge_index[1] = targets
    const int*   batch = (const int*)d_in[2];
    const float* W1 = (const float*)d_in[3];
    const float* b1 = (const float*)d_in[4];
    const float* W2 = (const float*)d_in[5];
    const float* b2 = (const float*)d_in[6];
    const float* W3 = (const float*)d_in[7];
    const float* b3 = (const float*)d_in[8];
    const float* Wl = (const float*)d_in[9];
    const float* bl = (const float*)d_in[10];
    float* out = (float*)d_out;

    // workspace layout (all offsets 64-element = 256B aligned)
    size_t cur = 0;
    auto take = [&](size_t elems) { size_t c = cur; cur += (elems + 63) & ~(size_t)63; return c; };
    float* base_f = (float*)d_ws;
    int*   base_i = (int*)d_ws;

    float*  dinv    = base_f + take(NN);
    int*    indeg   = base_i + take(NN);
    int*    csr_off = base_i + take(NN + 1);
    int*    cursor  = base_i + take(NN);
    int*    partial = base_i + take(SCAN_BLOCKS);
    float2* ew      = (float2*)(base_f + take((size_t)NE * 2));
    float*  tmp     = base_f + take((size_t)NN * 64);
    float*  h       = base_f + take((size_t)NN * 64);
    float*  gg      = base_f + take(2 * NG);   // gsum | gcnt contiguous
    float*  gsum    = gg;
    float*  gcnt    = gg + NG;
    (void)ws_size; (void)n_in; (void)in_sizes; (void)out_size;

    hipMemsetAsync(indeg, 0, NN * sizeof(int), stream);
    hipMemsetAsync(gg, 0, 2 * NG * sizeof(float), stream);

    const int nblk_pull = (NN + 3) / 4;

    // ---- layer-1 GEMM fused with degree histogram (independent) ----
    gemm_deg_kernel<DIN><<<GEMM_BLOCKS + DEG_BLOCKS, 256, 0, stream>>>(
        x, W1, tmp, NN, col, indeg, NE);
    // ---- coalesced 3-phase scan (+ dinv/cursor fused into phase C) ----
    scan_phaseA<<<SCAN_BLOCKS, 256, 0, stream>>>(indeg, partial, NN);
    scan_phaseB<<<1, 256, 0, stream>>>(partial, SCAN_BLOCKS);
    scan_phaseC<<<SCAN_BLOCKS, 256, 0, stream>>>(indeg, partial, csr_off, cursor, dinv, NN);
    // ---- CSR fill ----
    fill_kernel<<<FILL_BLOCKS, 256, 0, stream>>>(row, col, dinv, cursor, ew, NE);

    // ---- layer 1 pull ----
    pull_kernel<<<nblk_pull, 256, 0, stream>>>(tmp, csr_off, ew, dinv, b1, h, NN);

    // ---- layer 2 ----
    gemm_kernel<DH><<<GEMM_BLOCKS, 256, 0, stream>>>(h, W2, tmp, NN);
    pull_kernel<<<nblk_pull, 256, 0, stream>>>(tmp, csr_off, ew, dinv, b2, h, NN);

    // ---- layer 3 ----
    gemm_kernel<DH><<<GEMM_BLOCKS, 256, 0, stream>>>(h, W3, tmp, NN);
    pull_kernel<<<nblk_pull, 256, 0, stream>>>(tmp, csr_off, ew, dinv, b3, h, NN);

    // ---- final linear + mean pool ----
    final_pool_kernel<<<POOL_BLOCKS, 256, 0, stream>>>(h, Wl, batch, gsum, gcnt, NN);
    pool_div_kernel<<<1, 64, 0, stream>>>(gsum, gcnt, bl, out);
}

// Round 9
// 333.748 us; speedup vs baseline: 1.4561x; 1.0666x over previous
//
#include <hip/hip_runtime.h>
#include <math.h>

#define NN 50000
#define NE 800000
#define DIN 128
#define DH 64
#define NG 64

#define GEMM_BLOCKS ((NN + 63) / 64)     // 782
#define DEG_BLOCKS 2048
#define FILL_BLOCKS 2048
#define SCAN_BLOCKS ((NN + 255) / 256)   // 196

// ---------------- hybrid: gemm layer1 + degree histogram (independent work) ----------------
template <int K>
__global__ __launch_bounds__(256, 4) void gemm_deg_kernel(const float* __restrict__ in,
                                                          const float* __restrict__ W,
                                                          float* __restrict__ out, int n,
                                                          const int* __restrict__ col,
                                                          int* __restrict__ indeg, int e) {
    __shared__ float Ws[K * 64];
    if (blockIdx.x >= GEMM_BLOCKS) {
        int i = (blockIdx.x - GEMM_BLOCKS) * 256 + threadIdx.x;
        int stride = DEG_BLOCKS * 256;
        for (; i < e; i += stride) atomicAdd(&indeg[col[i]], 1);
        return;
    }
    for (int t = threadIdx.x; t < K * 16; t += 256)
        reinterpret_cast<float4*>(Ws)[t] = reinterpret_cast<const float4*>(W)[t];
    __syncthreads();

    int w = threadIdx.x >> 6, l = threadIdx.x & 63;
    int fq = l & 15;
    int nl = l >> 4;
    int base = blockIdx.x * 64 + w * 16 + nl * 4;

    const float* r0 = in + (size_t)min(base + 0, n - 1) * K;
    const float* r1 = in + (size_t)min(base + 1, n - 1) * K;
    const float* r2 = in + (size_t)min(base + 2, n - 1) * K;
    const float* r3 = in + (size_t)min(base + 3, n - 1) * K;

    float acc[4][4];
    #pragma unroll
    for (int i = 0; i < 4; ++i)
        #pragma unroll
        for (int f = 0; f < 4; ++f) acc[i][f] = 0.f;

    #pragma unroll 2
    for (int k = 0; k < K; k += 4) {
        float4 wv[4];
        #pragma unroll
        for (int kk = 0; kk < 4; ++kk)
            wv[kk] = *reinterpret_cast<const float4*>(&Ws[(k + kk) * 64 + 4 * fq]);
        float4 xv[4];
        xv[0] = *reinterpret_cast<const float4*>(r0 + k);
        xv[1] = *reinterpret_cast<const float4*>(r1 + k);
        xv[2] = *reinterpret_cast<const float4*>(r2 + k);
        xv[3] = *reinterpret_cast<const float4*>(r3 + k);
        #pragma unroll
        for (int i = 0; i < 4; ++i) {
            float xs[4] = {xv[i].x, xv[i].y, xv[i].z, xv[i].w};
            #pragma unroll
            for (int kk = 0; kk < 4; ++kk) {
                acc[i][0] = fmaf(xs[kk], wv[kk].x, acc[i][0]);
                acc[i][1] = fmaf(xs[kk], wv[kk].y, acc[i][1]);
                acc[i][2] = fmaf(xs[kk], wv[kk].z, acc[i][2]);
                acc[i][3] = fmaf(xs[kk], wv[kk].w, acc[i][3]);
            }
        }
    }

    #pragma unroll
    for (int i = 0; i < 4; ++i) {
        int node = base + i;
        if (node < n) {
            float4 o = make_float4(acc[i][0], acc[i][1], acc[i][2], acc[i][3]);
            *reinterpret_cast<float4*>(&out[(size_t)node * 64 + 4 * fq]) = o;
        }
    }
}

// ---------------- GEMM (layers 2,3) ----------------
// Round-4 lesson: full K unroll -> 256 VGPR + scratch spill. unroll 2 + lb(256,4).
template <int K>
__global__ __launch_bounds__(256, 4) void gemm_kernel(const float* __restrict__ in,
                                                      const float* __restrict__ W,
                                                      float* __restrict__ out, int n) {
    __shared__ float Ws[K * 64];
    for (int t = threadIdx.x; t < K * 16; t += 256)
        reinterpret_cast<float4*>(Ws)[t] = reinterpret_cast<const float4*>(W)[t];
    __syncthreads();

    int w = threadIdx.x >> 6, l = threadIdx.x & 63;
    int fq = l & 15;
    int nl = l >> 4;
    int base = blockIdx.x * 64 + w * 16 + nl * 4;

    const float* r0 = in + (size_t)min(base + 0, n - 1) * K;
    const float* r1 = in + (size_t)min(base + 1, n - 1) * K;
    const float* r2 = in + (size_t)min(base + 2, n - 1) * K;
    const float* r3 = in + (size_t)min(base + 3, n - 1) * K;

    float acc[4][4];
    #pragma unroll
    for (int i = 0; i < 4; ++i)
        #pragma unroll
        for (int f = 0; f < 4; ++f) acc[i][f] = 0.f;

    #pragma unroll 2
    for (int k = 0; k < K; k += 4) {
        float4 wv[4];
        #pragma unroll
        for (int kk = 0; kk < 4; ++kk)
            wv[kk] = *reinterpret_cast<const float4*>(&Ws[(k + kk) * 64 + 4 * fq]);
        float4 xv[4];
        xv[0] = *reinterpret_cast<const float4*>(r0 + k);
        xv[1] = *reinterpret_cast<const float4*>(r1 + k);
        xv[2] = *reinterpret_cast<const float4*>(r2 + k);
        xv[3] = *reinterpret_cast<const float4*>(r3 + k);
        #pragma unroll
        for (int i = 0; i < 4; ++i) {
            float xs[4] = {xv[i].x, xv[i].y, xv[i].z, xv[i].w};
            #pragma unroll
            for (int kk = 0; kk < 4; ++kk) {
                acc[i][0] = fmaf(xs[kk], wv[kk].x, acc[i][0]);
                acc[i][1] = fmaf(xs[kk], wv[kk].y, acc[i][1]);
                acc[i][2] = fmaf(xs[kk], wv[kk].z, acc[i][2]);
                acc[i][3] = fmaf(xs[kk], wv[kk].w, acc[i][3]);
            }
        }
    }

    #pragma unroll
    for (int i = 0; i < 4; ++i) {
        int node = base + i;
        if (node < n) {
            float4 o = make_float4(acc[i][0], acc[i][1], acc[i][2], acc[i][3]);
            *reinterpret_cast<float4*>(&out[(size_t)node * 64 + 4 * fq]) = o;
        }
    }
}

// ---------------- 3-phase coalesced multi-block scan ----------------
__global__ __launch_bounds__(256) void scan_phaseA(const int* __restrict__ indeg,
                                                   int* __restrict__ partial, int n) {
    int i = blockIdx.x * 256 + threadIdx.x;
    int v = (i < n) ? indeg[i] : 0;
    int s = v;
    #pragma unroll
    for (int d = 1; d < 64; d <<= 1) s += __shfl_xor(s, d, 64);
    __shared__ int ws[4];
    if ((threadIdx.x & 63) == 0) ws[threadIdx.x >> 6] = s;
    __syncthreads();
    if (threadIdx.x == 0) partial[blockIdx.x] = ws[0] + ws[1] + ws[2] + ws[3];
}

__global__ __launch_bounds__(256) void scan_phaseB(int* __restrict__ partial, int nb) {
    int t = threadIdx.x;
    int lane = t & 63, wid = t >> 6;
    int v = (t < nb) ? partial[t] : 0;
    int inc = v;
    #pragma unroll
    for (int d = 1; d < 64; d <<= 1) {
        int u = __shfl_up(inc, d, 64);
        if (lane >= d) inc += u;
    }
    __shared__ int ws[4];
    if (lane == 63) ws[wid] = inc;
    __syncthreads();
    int woff = 0;
    #pragma unroll
    for (int k = 0; k < 4; ++k) woff += (k < wid) ? ws[k] : 0;
    if (t < nb) partial[t] = woff + inc - v;   // exclusive
}

__global__ __launch_bounds__(256) void scan_phaseC(const int* __restrict__ indeg,
                                                   const int* __restrict__ partial,
                                                   int* __restrict__ off,
                                                   int* __restrict__ cursor,
                                                   float* __restrict__ dinv, int n) {
    int i = blockIdx.x * 256 + threadIdx.x;
    int d = (i < n) ? indeg[i] : 0;
    int lane = threadIdx.x & 63, wid = threadIdx.x >> 6;
    int inc = d;
    #pragma unroll
    for (int dd = 1; dd < 64; dd <<= 1) {
        int u = __shfl_up(inc, dd, 64);
        if (lane >= dd) inc += u;
    }
    __shared__ int ws[4];
    if (lane == 63) ws[wid] = inc;
    __syncthreads();
    int woff = 0;
    #pragma unroll
    for (int k = 0; k < 4; ++k) woff += (k < wid) ? ws[k] : 0;
    int excl = partial[blockIdx.x] + woff + inc - d;
    if (i < n) {
        off[i] = excl;
        cursor[i] = excl;
        dinv[i] = rsqrtf((float)(d + 1));
        if (i == n - 1) off[n] = excl + d;
    }
}

// bucket edges by target: ew[p] = { bitcast(src), dinv[src]*dinv[col] }
__global__ void fill_kernel(const int* __restrict__ row, const int* __restrict__ col,
                            const float* __restrict__ dinv, int* __restrict__ cursor,
                            float2* __restrict__ ew, int e) {
    int i = blockIdx.x * blockDim.x + threadIdx.x;
    int stride = gridDim.x * blockDim.x;
    for (; i < e; i += stride) {
        int c = col[i], r = row[i];
        int p = atomicAdd(&cursor[c], 1);
        ew[p] = make_float2(__int_as_float(r), dinv[r] * dinv[c]);
    }
}

// ---------------- pull aggregation + bias + ELU ----------------
// Round-8 restructure: wave = 1 node, lane = (e4, fg): fg = feature-quad
// (features 4*fg..4*fg+3), e4 = edge slot. One float4 gather instruction
// fetches 4 edges' feature-quads (16B/lane, 1KB/instr) -> ~3x fewer VMEM
// instructions than scalar-gather version. Butterfly over e4 (xor 16,32) at
// the end; self-loop + bias folded after the reduction.
__global__ __launch_bounds__(256) void pull_kernel(const float* __restrict__ tmp,
                                                   const int* __restrict__ off,
                                                   const float2* __restrict__ ew,
                                                   const float* __restrict__ dinv,
                                                   const float* __restrict__ bias,
                                                   float* __restrict__ out, int n) {
    int wid = threadIdx.x >> 6;
    int lane = threadIdx.x & 63;
    int node = blockIdx.x * 4 + wid;
    if (node >= n) return;
    int fg = lane & 15, e4 = lane >> 4;
    const float4* trow = reinterpret_cast<const float4*>(tmp);

    float4 acc = make_float4(0.f, 0.f, 0.f, 0.f);
    int e = off[node], s1 = off[node + 1];

    // 8 edges in flight per iteration (2 float4 gathers per lane)
    for (; e + 8 <= s1; e += 8) {
        float2 m0 = ew[e + e4];
        float2 m1 = ew[e + 4 + e4];
        float4 v0 = trow[(size_t)__float_as_int(m0.x) * 16 + fg];
        float4 v1 = trow[(size_t)__float_as_int(m1.x) * 16 + fg];
        acc.x = fmaf(v0.x, m0.y, acc.x);
        acc.y = fmaf(v0.y, m0.y, acc.y);
        acc.z = fmaf(v0.z, m0.y, acc.z);
        acc.w = fmaf(v0.w, m0.y, acc.w);
        acc.x = fmaf(v1.x, m1.y, acc.x);
        acc.y = fmaf(v1.y, m1.y, acc.y);
        acc.z = fmaf(v1.z, m1.y, acc.z);
        acc.w = fmaf(v1.w, m1.y, acc.w);
    }
    // predicated tail (<=7 edges)
    for (; e < s1; e += 4) {
        int idx = e + e4;
        if (idx < s1) {
            float2 m = ew[idx];
            float4 v = trow[(size_t)__float_as_int(m.x) * 16 + fg];
            acc.x = fmaf(v.x, m.y, acc.x);
            acc.y = fmaf(v.y, m.y, acc.y);
            acc.z = fmaf(v.z, m.y, acc.z);
            acc.w = fmaf(v.w, m.y, acc.w);
        }
    }

    // reduce over e4 (lanes 0..15 / 16..31 / 32..47 / 48..63 hold partials)
    acc.x += __shfl_xor(acc.x, 16, 64);
    acc.y += __shfl_xor(acc.y, 16, 64);
    acc.z += __shfl_xor(acc.z, 16, 64);
    acc.w += __shfl_xor(acc.w, 16, 64);
    acc.x += __shfl_xor(acc.x, 32, 64);
    acc.y += __shfl_xor(acc.y, 32, 64);
    acc.z += __shfl_xor(acc.z, 32, 64);
    acc.w += __shfl_xor(acc.w, 32, 64);

    float dt = dinv[node];
    float s2 = dt * dt;
    float4 self = trow[(size_t)node * 16 + fg];
    float4 b4 = reinterpret_cast<const float4*>(bias)[fg];
    float4 r;
    r.x = acc.x + self.x * s2 + b4.x;
    r.y = acc.y + self.y * s2 + b4.y;
    r.z = acc.z + self.z * s2 + b4.z;
    r.w = acc.w + self.w * s2 + b4.w;
    r.x = (r.x > 0.f) ? r.x : expm1f(r.x);
    r.y = (r.y > 0.f) ? r.y : expm1f(r.y);
    r.z = (r.z > 0.f) ? r.z : expm1f(r.z);
    r.w = (r.w > 0.f) ? r.w : expm1f(r.w);
    if (e4 == 0)
        reinterpret_cast<float4*>(out)[(size_t)node * 16 + fg] = r;
}

// ---------------- final linear + grouped mean-pool partials ----------------
#define POOL_BLOCKS 256
__global__ __launch_bounds__(256) void final_pool_kernel(const float* __restrict__ h,
                                                         const float* __restrict__ Wl,
                                                         const int* __restrict__ batch,
                                                         float* __restrict__ gsum,
                                                         float* __restrict__ gcnt, int n) {
    __shared__ float lsum[NG];
    __shared__ float lcnt[NG];
    if (threadIdx.x < NG) { lsum[threadIdx.x] = 0.f; lcnt[threadIdx.x] = 0.f; }
    __syncthreads();
    int wid = threadIdx.x >> 6, lane = threadIdx.x & 63;
    float wl = Wl[lane];
    int per_block = (n + POOL_BLOCKS - 1) / POOL_BLOCKS;
    int start = blockIdx.x * per_block;
    int end = start + per_block;
    if (end > n) end = n;
    for (int node = start + wid; node < end; node += 4) {
        float p = h[(size_t)node * 64 + lane] * wl;
        #pragma unroll
        for (int d = 32; d >= 1; d >>= 1) p += __shfl_xor(p, d, 64);
        if (lane == 0) {
            int g = batch[node];
            atomicAdd(&lsum[g], p);
            atomicAdd(&lcnt[g], 1.f);
        }
    }
    __syncthreads();
    if (threadIdx.x < NG && lcnt[threadIdx.x] != 0.f) {
        atomicAdd(&gsum[threadIdx.x], lsum[threadIdx.x]);
        atomicAdd(&gcnt[threadIdx.x], lcnt[threadIdx.x]);
    }
}

__global__ void pool_div_kernel(const float* __restrict__ gsum, const float* __restrict__ gcnt,
                                const float* __restrict__ bl, float* __restrict__ out) {
    int g = threadIdx.x;
    if (g < NG) {
        float c = gcnt[g];
        out[g] = (c > 0.5f) ? (gsum[g] / c + bl[0]) : 0.f;
    }
}

extern "C" void kernel_launch(void* const* d_in, const int* in_sizes, int n_in,
                              void* d_out, int out_size, void* d_ws, size_t ws_size,
                              hipStream_t stream) {
    const float* x    = (const float*)d_in[0];
    const int*   eidx = (const int*)d_in[1];
    const int*   row  = eidx;              // edge_index[0] = sources
    const int*   col  = eidx + NE;         // edge_index[1] = targets
    const int*   batch = (const int*)d_in[2];
    const float* W1 = (const float*)d_in[3];
    const float* b1 = (const float*)d_in[4];
    const float* W2 = (const float*)d_in[5];
    const float* b2 = (const float*)d_in[6];
    const float* W3 = (const float*)d_in[7];
    const float* b3 = (const float*)d_in[8];
    const float* Wl = (const float*)d_in[9];
    const float* bl = (const float*)d_in[10];
    float* out = (float*)d_out;

    // workspace layout (all offsets 64-element = 256B aligned)
    size_t cur = 0;
    auto take = [&](size_t elems) { size_t c = cur; cur += (elems + 63) & ~(size_t)63; return c; };
    float* base_f = (float*)d_ws;
    int*   base_i = (int*)d_ws;

    float*  dinv    = base_f + take(NN);
    int*    indeg   = base_i + take(NN);
    int*    csr_off = base_i + take(NN + 1);
    int*    cursor  = base_i + take(NN);
    int*    partial = base_i + take(SCAN_BLOCKS);
    float2* ew      = (float2*)(base_f + take((size_t)NE * 2));
    float*  tmp     = base_f + take((size_t)NN * 64);
    float*  h       = base_f + take((size_t)NN * 64);
    float*  gg      = base_f + take(2 * NG);   // gsum | gcnt contiguous
    float*  gsum    = gg;
    float*  gcnt    = gg + NG;
    (void)ws_size; (void)n_in; (void)in_sizes; (void)out_size;

    hipMemsetAsync(indeg, 0, NN * sizeof(int), stream);
    hipMemsetAsync(gg, 0, 2 * NG * sizeof(float), stream);

    const int nblk_pull = (NN + 3) / 4;

    // ---- layer-1 GEMM fused with degree histogram (independent) ----
    gemm_deg_kernel<DIN><<<GEMM_BLOCKS + DEG_BLOCKS, 256, 0, stream>>>(
        x, W1, tmp, NN, col, indeg, NE);
    // ---- coalesced 3-phase scan (+ dinv/cursor fused into phase C) ----
    scan_phaseA<<<SCAN_BLOCKS, 256, 0, stream>>>(indeg, partial, NN);
    scan_phaseB<<<1, 256, 0, stream>>>(partial, SCAN_BLOCKS);
    scan_phaseC<<<SCAN_BLOCKS, 256, 0, stream>>>(indeg, partial, csr_off, cursor, dinv, NN);
    // ---- CSR fill ----
    fill_kernel<<<FILL_BLOCKS, 256, 0, stream>>>(row, col, dinv, cursor, ew, NE);

    // ---- layer 1 pull ----
    pull_kernel<<<nblk_pull, 256, 0, stream>>>(tmp, csr_off, ew, dinv, b1, h, NN);

    // ---- layer 2 ----
    gemm_kernel<DH><<<GEMM_BLOCKS, 256, 0, stream>>>(h, W2, tmp, NN);
    pull_kernel<<<nblk_pull, 256, 0, stream>>>(tmp, csr_off, ew, dinv, b2, h, NN);

    // ---- layer 3 ----
    gemm_kernel<DH><<<GEMM_BLOCKS, 256, 0, stream>>>(h, W3, tmp, NN);
    pull_kernel<<<nblk_pull, 256, 0, stream>>>(tmp, csr_off, ew, dinv, b3, h, NN);

    // ---- final linear + mean pool ----
    final_pool_kernel<<<POOL_BLOCKS, 256, 0, stream>>>(h, Wl, batch, gsum, gcnt, NN);
    pool_div_kernel<<<1, 64, 0, stream>>>(gsum, gcnt, bl, out);
}